// Round 1
// baseline (455.400 us; speedup 1.0000x reference)
//
#include <hip/hip_runtime.h>

// Hungarian matcher cost matrix: out[b,n,m] = cost_class + cost_mask + cost_dice
//   dot[b,n,m]  = sum_l sigmoid(p[b,n,l]) * t[b,m,l]
//   sum_p[b,n]  = sum_l sigmoid(p[b,n,l])
//   sum_t[b,m]  = sum_l t[b,m,l]
//   cost_class  = -logits[b,n,label[b,m]]
//   cost_mask   = -(2*dot + L - sum_p - sum_t) / L
//   cost_dice   = 1 - (2*dot + 1) / (sum_p + sum_t + 1)

#define Lsz 65536
#define Bb 4
#define Nn 100
#define Mm 20
#define Cc 81
#define Pp 2120        // partials per (b,kb) block: 2000 dot + 100 sum_p + 20 sum_t
#define CS 64          // LDS staging sub-chunk (floats per p-row)
#define LDS_STRIDE 68  // CS + 4 pad: stride ≡ 4 (mod 32) -> conflict-free b128

__device__ __forceinline__ float sigmoid_fast(float x) {
    // 1/(1+exp(-x)) = rcp(1 + exp2(-x*log2(e)))
    float e = __builtin_amdgcn_exp2f(x * -1.44269504088896340736f);
    return __builtin_amdgcn_rcpf(1.0f + e);
}

__global__ __launch_bounds__(128) void hung_main(
    const float* __restrict__ pm,   // (B,N,L) pred_masks
    const float* __restrict__ gm,   // (B,M,L) gt_masks
    float* __restrict__ ws,         // (B,KB,Pp) partials
    int KB, int R)                  // R = Lsz/KB, multiple of CS
{
    __shared__ float lds_p[Nn * LDS_STRIDE];
    __shared__ float lds_t[Mm];

    const int tid = threadIdx.x;
    const int kb  = blockIdx.x;
    const int b   = blockIdx.y;
    const int l0  = kb * R;

    // ---- Phase 1: per-block gt_mask partial sums (also warms t-lines into L2)
    {
        const int wv   = tid >> 6;   // wave id 0/1
        const int lane = tid & 63;
        for (int m = wv; m < Mm; m += 2) {
            float s = 0.f;
            const float4* t4 = (const float4*)(gm + (size_t)(b * Mm + m) * Lsz + l0);
            for (int q = lane; q < (R >> 2); q += 64) {
                float4 v = t4[q];
                s += (v.x + v.y) + (v.z + v.w);
            }
            #pragma unroll
            for (int off = 32; off > 0; off >>= 1)
                s += __shfl_down(s, off, 64);
            if (lane == 0) lds_t[m] = s;
        }
    }

    // ---- Phase 2: split-K dot products. Thread n owns all 20 accumulators.
    float acc[Mm];
    #pragma unroll
    for (int m = 0; m < Mm; ++m) acc[m] = 0.f;
    float sum_p = 0.f;

    const int S = R / CS;
    const float* prow = pm + (size_t)b * Nn * Lsz + l0;
    const float* tb   = gm + (size_t)b * Mm * Lsz;

    for (int s = 0; s < S; ++s) {
        __syncthreads();
        // stage 100 rows x 64 floats, coalesced float4
        for (int idx = tid; idx < Nn * (CS / 4); idx += 128) {
            int r = idx >> 4;
            int q = idx & 15;
            float4 v = *(const float4*)(prow + (size_t)r * Lsz + s * CS + 4 * q);
            *(float4*)&lds_p[r * LDS_STRIDE + 4 * q] = v;
        }
        __syncthreads();

        if (tid < Nn) {
            const int lbase0 = l0 + s * CS;
            #pragma unroll 1
            for (int lq = 0; lq < CS / 4; ++lq) {
                float4 p4 = *(const float4*)&lds_p[tid * LDS_STRIDE + 4 * lq];
                float pv0 = sigmoid_fast(p4.x);
                float pv1 = sigmoid_fast(p4.y);
                float pv2 = sigmoid_fast(p4.z);
                float pv3 = sigmoid_fast(p4.w);
                sum_p += (pv0 + pv1) + (pv2 + pv3);
                const int lb = lbase0 + 4 * lq;
                // t address is wave-uniform -> s_load_dwordx4; FMA takes SGPR src
                #pragma unroll
                for (int m = 0; m < Mm; ++m) {
                    float4 tv = *(const float4*)(tb + (size_t)m * Lsz + lb);
                    acc[m] = fmaf(tv.x, pv0, acc[m]);
                    acc[m] = fmaf(tv.y, pv1, acc[m]);
                    acc[m] = fmaf(tv.z, pv2, acc[m]);
                    acc[m] = fmaf(tv.w, pv3, acc[m]);
                }
            }
        }
    }

    // ---- Phase 3: write partials (coalesced; layout j = m*100+n | 2000+n | 2100+m)
    float* wsb = ws + (size_t)(b * KB + kb) * Pp;
    if (tid < Nn) {
        #pragma unroll
        for (int m = 0; m < Mm; ++m)
            wsb[m * Nn + tid] = acc[m];
        wsb[2000 + tid] = sum_p;
    }
    if (tid < Mm) wsb[2100 + tid] = lds_t[tid];  // phase-1 writes ordered by first barrier
}

__global__ __launch_bounds__(256) void hung_finalize(
    const float* __restrict__ ws,
    const float* __restrict__ logits,   // (B,N,C)
    const int*   __restrict__ labels,   // (B,M)
    float* __restrict__ out,            // (B,N,M)
    int KB)
{
    int t = blockIdx.x * 256 + threadIdx.x;
    if (t >= Bb * Nn * Mm) return;
    int b = t / (Nn * Mm);
    int r = t % (Nn * Mm);
    int m = r / Nn;           // n fast-varying across consecutive threads -> coalesced ws reads
    int n = r % Nn;

    const float* p = ws + (size_t)b * KB * Pp;
    float dot = 0.f, sp = 0.f, st = 0.f;
    #pragma unroll 4
    for (int kb = 0; kb < KB; ++kb) {
        dot += p[m * Nn + n];
        sp  += p[2000 + n];
        st  += p[2100 + m];
        p += Pp;
    }

    int lab = labels[b * Mm + m];
    float cc = -logits[(size_t)(b * Nn + n) * Cc + lab];
    const float invL = 1.0f / (float)Lsz;
    float cm = -(2.f * dot + (float)Lsz - sp - st) * invL;
    float cd = 1.f - (2.f * dot + 1.f) / (sp + st + 1.f);
    out[(size_t)b * (Nn * Mm) + n * Mm + m] = cc + cm + cd;
}

extern "C" void kernel_launch(void* const* d_in, const int* in_sizes, int n_in,
                              void* d_out, int out_size, void* d_ws, size_t ws_size,
                              hipStream_t stream) {
    const float* logits = (const float*)d_in[0];  // (4,100,81)
    const float* pmasks = (const float*)d_in[1];  // (4,100,256,256)
    const int*   labels = (const int*)d_in[2];    // (4,20)
    const float* gmasks = (const float*)d_in[3];  // (4,20,256,256)
    float* out = (float*)d_out;
    float* ws  = (float*)d_ws;

    // pick split-K factor so the partial buffer fits in ws
    int KB = 256;
    while (KB > 1 && (size_t)Bb * KB * Pp * sizeof(float) > ws_size) KB >>= 1;
    int R = Lsz / KB;

    hung_main<<<dim3(KB, Bb), 128, 0, stream>>>(pmasks, gmasks, ws, KB, R);
    hung_finalize<<<(Bb * Nn * Mm + 255) / 256, 256, 0, stream>>>(ws, logits, labels, out, KB);
}

// Round 2
// 200.923 us; speedup vs baseline: 2.2665x; 2.2665x over previous
//
#include <hip/hip_runtime.h>

// out[b,n,m] = cost_class + cost_mask + cost_dice
//   dot[b,n,m] = sum_l sigmoid(p[b,n,l]) * t[b,m,l]   (bf16 MFMA, fp32 acc)
//   sum_p[b,n] = sum_l sigmoid(p)  (fp32, exact path)
//   sum_t[b,m] = sum_l t           (fp32, exact path)
//   cost_class = -logits[b,n,label[b,m]]
//   cost_mask  = -(2*dot + L - sum_p - sum_t)/L
//   cost_dice  = 1 - (2*dot + 1)/(sum_p + sum_t + 1)

#define Lsz 65536
#define Bb 4
#define Nn 100
#define Mm 20
#define Cc 81
#define CS 128                  // l-chunk per staging pass
#define NP 112                  // padded N stride in ws dot region
#define Pp (20 * NP + NP + 32)  // 2240 dot + 112 sum_p + 32 sum_t(padded) = 2384
#define KSTR 136                // LDS row stride in ushorts (128 bf16 + 8 pad; 272B = 17*16)

typedef short bf16x8 __attribute__((ext_vector_type(8)));
typedef float fx4 __attribute__((ext_vector_type(4)));

__device__ __forceinline__ float sigmoid_fast(float x) {
    float e = __builtin_amdgcn_exp2f(x * -1.44269504088896340736f);
    return __builtin_amdgcn_rcpf(1.0f + e);
}

__device__ __forceinline__ ushort bf16rne(float f) {
    union { float f; unsigned u; } v; v.f = f;
    unsigned u = v.u;
    u += 0x7fffu + ((u >> 16) & 1u);
    return (ushort)(u >> 16);
}

__global__ __launch_bounds__(256) void hung_main(
    const float* __restrict__ pm,   // (B,N,L)
    const float* __restrict__ gm,   // (B,M,L)
    float* __restrict__ ws,         // (B,KBW,Pp)
    int KBW, int NCH)
{
    __shared__ __align__(16) ushort ldsA[NP * KSTR];  // sigma(p) bf16, [n][k]
    __shared__ __align__(16) ushort ldsB[32 * KSTR];  // t bf16, [m][k]

    const int tid  = threadIdx.x;
    const int slot = blockIdx.x;
    const int b    = blockIdx.y;
    const int q    = tid & 31;        // float4-quad within 128-float row chunk
    const int rr   = tid >> 5;        // 0..7, row phase
    const int lane = tid & 63;
    const int w    = tid >> 6;        // wave 0..3
    const int lr   = lane & 15;
    const int kg   = lane >> 4;       // 0..3

    float sp[13], st[3];
    #pragma unroll
    for (int p = 0; p < 13; ++p) sp[p] = 0.f;
    #pragma unroll
    for (int p = 0; p < 3; ++p) st[p] = 0.f;

    fx4 acc00 = {0.f, 0.f, 0.f, 0.f};
    fx4 acc01 = {0.f, 0.f, 0.f, 0.f};
    fx4 acc10 = {0.f, 0.f, 0.f, 0.f};
    fx4 acc11 = {0.f, 0.f, 0.f, 0.f};

    const float* pbase = pm + (size_t)b * Nn * Lsz + 4 * q;
    const float* tbase = gm + (size_t)b * Mm * Lsz + 4 * q;

    for (int c = 0; c < NCH; ++c) {
        const int l0 = (slot * NCH + c) * CS;
        __syncthreads();  // prev chunk's LDS reads done before overwrite

        // ---- stage A: sigma(pred_masks) -> bf16 LDS [n][k]
        #pragma unroll
        for (int p = 0; p < 13; ++p) {
            const int r = rr + 8 * p;
            if (r < Nn) {
                float4 v = *(const float4*)(pbase + (size_t)r * Lsz + l0);
                float s0 = sigmoid_fast(v.x), s1 = sigmoid_fast(v.y);
                float s2 = sigmoid_fast(v.z), s3 = sigmoid_fast(v.w);
                sp[p] += (s0 + s1) + (s2 + s3);
                ushort4 o = { bf16rne(s0), bf16rne(s1), bf16rne(s2), bf16rne(s3) };
                *(ushort4*)&ldsA[r * KSTR + 4 * q] = o;
            }
        }
        // ---- stage B: gt_masks -> bf16 LDS [m][k]
        #pragma unroll
        for (int p = 0; p < 3; ++p) {
            const int r = rr + 8 * p;
            if (r < Mm) {
                float4 v = *(const float4*)(tbase + (size_t)r * Lsz + l0);
                st[p] += (v.x + v.y) + (v.z + v.w);
                ushort4 o = { bf16rne(v.x), bf16rne(v.y), bf16rne(v.z), bf16rne(v.w) };
                *(ushort4*)&ldsB[r * KSTR + 4 * q] = o;
            }
        }
        __syncthreads();

        // ---- MFMA: wave w owns n-tiles {2w, 2w+1}, m-tiles {0,1}
        #pragma unroll
        for (int kk = 0; kk < 4; ++kk) {
            const int ko = kk * 32 + kg * 8;  // ushort offset within row
            bf16x8 a0 = *(const bf16x8*)&ldsA[(32 * w + lr) * KSTR + ko];
            bf16x8 b0 = *(const bf16x8*)&ldsB[lr * KSTR + ko];
            bf16x8 b1 = *(const bf16x8*)&ldsB[(16 + lr) * KSTR + ko];
            acc00 = __builtin_amdgcn_mfma_f32_16x16x32_bf16(a0, b0, acc00, 0, 0, 0);
            acc01 = __builtin_amdgcn_mfma_f32_16x16x32_bf16(a0, b1, acc01, 0, 0, 0);
            if (w < 3) {  // n-tile 7 (rows 112..127) doesn't exist
                bf16x8 a1 = *(const bf16x8*)&ldsA[(32 * w + 16 + lr) * KSTR + ko];
                acc10 = __builtin_amdgcn_mfma_f32_16x16x32_bf16(a1, b0, acc10, 0, 0, 0);
                acc11 = __builtin_amdgcn_mfma_f32_16x16x32_bf16(a1, b1, acc11, 0, 0, 0);
            }
        }
    }

    // ---- reduce sum_p / sum_t across the 32 q-lanes of each row group
    #pragma unroll
    for (int p = 0; p < 13; ++p)
        #pragma unroll
        for (int o = 16; o > 0; o >>= 1) sp[p] += __shfl_xor(sp[p], o, 32);
    #pragma unroll
    for (int p = 0; p < 3; ++p)
        #pragma unroll
        for (int o = 16; o > 0; o >>= 1) st[p] += __shfl_xor(st[p], o, 32);

    float* wsb = ws + (size_t)(b * KBW + slot) * Pp;
    if ((tid & 31) == 0) {
        #pragma unroll
        for (int p = 0; p < 13; ++p) {
            const int r = rr + 8 * p;
            if (r < Nn) wsb[20 * NP + r] = sp[p];
        }
        #pragma unroll
        for (int p = 0; p < 3; ++p) {
            const int r = rr + 8 * p;
            if (r < Mm) wsb[20 * NP + NP + r] = st[p];
        }
    }

    // ---- store dot partials: D col = lane&15 (m), row = kg*4 + reg (n-local)
    const int nb = 32 * w + kg * 4;
    #pragma unroll
    for (int e = 0; e < 4; ++e) {
        const int n0 = nb + e;
        if (n0 < Nn) {
            wsb[lr * NP + n0] = acc00[e];
            if (lr < 4) wsb[(16 + lr) * NP + n0] = acc01[e];
        }
        const int n1 = nb + 16 + e;
        if (w < 3 && n1 < Nn) {
            wsb[lr * NP + n1] = acc10[e];
            if (lr < 4) wsb[(16 + lr) * NP + n1] = acc11[e];
        }
    }
}

__global__ __launch_bounds__(256) void hung_fin(
    const float* __restrict__ ws,
    const float* __restrict__ logits,   // (B,N,C)
    const int*   __restrict__ labels,   // (B,M)
    float* __restrict__ out,            // (B,N,M)
    int KBW)
{
    int t = blockIdx.x * 256 + threadIdx.x;
    if (t >= Bb * Nn * Mm) return;
    int b = t / (Nn * Mm);
    int r = t % (Nn * Mm);
    int m = r / Nn;       // n fast-varying -> coalesced ws reads
    int n = r % Nn;

    const float* p = ws + (size_t)b * KBW * Pp;
    float dot = 0.f, sp = 0.f, st = 0.f;
    #pragma unroll 4
    for (int kb = 0; kb < KBW; ++kb) {
        dot += p[m * NP + n];
        sp  += p[20 * NP + n];
        st  += p[20 * NP + NP + m];
        p += Pp;
    }

    int lab = labels[b * Mm + m];
    float cc = -logits[(size_t)(b * Nn + n) * Cc + lab];
    const float invL = 1.0f / (float)Lsz;
    float cm = -(2.f * dot + (float)Lsz - sp - st) * invL;
    float cd = 1.f - (2.f * dot + 1.f) / (sp + st + 1.f);
    out[(size_t)b * (Nn * Mm) + n * Mm + m] = cc + cm + cd;
}

extern "C" void kernel_launch(void* const* d_in, const int* in_sizes, int n_in,
                              void* d_out, int out_size, void* d_ws, size_t ws_size,
                              hipStream_t stream) {
    const float* logits = (const float*)d_in[0];
    const float* pmasks = (const float*)d_in[1];
    const int*   labels = (const int*)d_in[2];
    const float* gmasks = (const float*)d_in[3];
    float* out = (float*)d_out;
    float* ws  = (float*)d_ws;

    int KBW = 128;  // split-K slots per batch; 4.9 MB of ws at 128
    while (KBW > 1 && (size_t)Bb * KBW * Pp * sizeof(float) > ws_size) KBW >>= 1;
    int NCH = (Lsz / CS) / KBW;  // chunks per block

    hung_main<<<dim3(KBW, Bb), 256, 0, stream>>>(pmasks, gmasks, ws, KBW, NCH);
    hung_fin<<<(Bb * Nn * Mm + 255) / 256, 256, 0, stream>>>(ws, logits, labels, out, KBW);
}